// Round 4
// baseline (381.476 us; speedup 1.0000x reference)
//
#include <hip/hip_runtime.h>
#include <hip/hip_bf16.h>

// Problem: out[s,:] = sum_{i in segment s} (input[i,:] @ W^T + b)
// N = 500000, S = 10000, D_IN = D_OUT = 128.
// Algebraic transform (linear ops commute):
//   out[s] = (sum_{i in seg s} X[i]) @ W^T + count_s * b
// Phase 0: zero Xs scratch (5.12 MB).
// Phase 1: WAVE-PRIVATE segment row-sum: each 64-lane wave owns a fixed
//          128-row window (64 KB contiguous stream). Piece reduction is one
//          shfl_xor(32) -- no barriers, no LDS, no vmcnt(0) drains. Interior
//          segments flush with plain stores; boundary pieces with f32 atomics.
// Phase 2: small GEMM (10000 x 128 x 128) + count*b epilogue.

#define D 128          // D_IN == D_OUT
#define D4 32          // D/4
#define WROWS 128      // rows per wave in phase 1

__device__ __forceinline__ void f4add(float4& a, const float4& v) {
  a.x += v.x; a.y += v.y; a.z += v.z; a.w += v.w;
}

// ---------------- Phase 0: zero the Xs scratch ----------------
__global__ __launch_bounds__(256) void zero_xs_kernel(float4* Xs4, int n4) {
  int i = blockIdx.x * 256 + threadIdx.x;
  if (i < n4) Xs4[i] = make_float4(0.f, 0.f, 0.f, 0.f);
}

// ---------------- Phase 1: wave-private segment row sum ----------------
// Lane layout: c4 = lane&31 (float4 column), rh = lane>>5 (row parity).
// One wave load instruction covers 2 rows x 512 B = 1 KB contiguous.
// Unroll x4 => 4 KB outstanding per wave. ~3907 waves, 64 KB each.
__global__ __launch_bounds__(256) void seg_sum_wave_kernel(
    const float* __restrict__ in, const int* __restrict__ graph,
    float* __restrict__ Xs, int N, int S) {
  int lane = threadIdx.x & 63;
  int wv   = threadIdx.x >> 6;
  int win  = blockIdx.x * 4 + wv;
  int w0   = win * WROWS;
  if (w0 >= N) return;                   // wave-uniform
  int wEnd = min(w0 + WROWS, N) - 1;     // inclusive

  int c4 = lane & 31;
  int rh = lane >> 5;                    // 0 or 1

  // binary search: largest s with graph[2s] <= w0 (starts sorted)
  int lo = 0, hi = S - 1;
  while (lo < hi) {
    int mid = (lo + hi + 1) >> 1;
    if (graph[2 * mid] <= w0) lo = mid; else hi = mid - 1;
  }

  const float4* in4 = (const float4*)in;
  int s = lo;
  while (true) {
    int rs       = graph[2 * s];
    int reRaw    = graph[2 * s + 1];
    int nxtStart = (s + 1 < S) ? graph[2 * s + 2] : N;
    int re       = min(reRaw, min(nxtStart - 1, N - 1));  // ref valid-mask
    int rs_c     = max(rs, 0);
    int a        = max(rs_c, w0);
    int b2       = min(re, wEnd);

    if (a <= b2) {                       // wave-uniform condition
      int len = b2 - a + 1;
      const float4* p = in4 + (size_t)(a + rh) * D4 + c4;
      float4 A0 = make_float4(0.f,0.f,0.f,0.f);
      float4 A1 = make_float4(0.f,0.f,0.f,0.f);
      float4 A2 = make_float4(0.f,0.f,0.f,0.f);
      float4 A3 = make_float4(0.f,0.f,0.f,0.f);
      int r = 0;
      for (; r + 8 <= len; r += 8) {     // 4 independent 16B loads in flight
        float4 v0 = p[(size_t)(r + 0) * D4];
        float4 v1 = p[(size_t)(r + 2) * D4];
        float4 v2 = p[(size_t)(r + 4) * D4];
        float4 v3 = p[(size_t)(r + 6) * D4];
        f4add(A0, v0); f4add(A1, v1); f4add(A2, v2); f4add(A3, v3);
      }
      for (; r + rh < len; r += 2)       // <=3 iters; exec-mask on odd len
        f4add(A0, p[(size_t)r * D4]);
      f4add(A0, A1); f4add(A2, A3); f4add(A0, A2);

      // fold row-parity halves: lane l <-> l^32 (same c4)
      float4 o;
      o.x = __shfl_xor(A0.x, 32, 64);
      o.y = __shfl_xor(A0.y, 32, 64);
      o.z = __shfl_xor(A0.z, 32, 64);
      o.w = __shfl_xor(A0.w, 32, 64);
      f4add(A0, o);

      bool full = (rs_c >= w0) && (re <= wEnd);  // sole owner of segment
      if (lane < 32) {
        if (full) {
          ((float4*)Xs)[(size_t)s * D4 + c4] = A0;
        } else {
          float* q = Xs + (size_t)s * D + c4 * 4;
          atomicAdd(q + 0, A0.x);
          atomicAdd(q + 1, A0.y);
          atomicAdd(q + 2, A0.z);
          atomicAdd(q + 3, A0.w);
        }
      }
    }
    if (s + 1 >= S || graph[2 * s + 2] > wEnd) break;
    ++s;
  }
}

// ---------------- Phase 2: out = Xs @ W^T + cnt*b ----------------
// Tile: 16 segments x 64 output cols per 256-thread block.
#define SEG_PB 16
#define OUT_PB 64
#define WT_STRIDE 65

__global__ __launch_bounds__(256) void seg_gemm_kernel(
    const float* __restrict__ Xs, const float* __restrict__ W,
    const float* __restrict__ b, const int* __restrict__ graph,
    float* __restrict__ out, int N, int S) {
  __shared__ float Wt[D * WT_STRIDE];             // 33.3 KB
  __shared__ __align__(16) float XsL[SEG_PB * D]; // 8 KB
  __shared__ float cntL[SEG_PB];

  int tid   = threadIdx.x;
  int s0    = blockIdx.x * SEG_PB;
  int oBase = blockIdx.y * OUT_PB;

  #pragma unroll
  for (int rnd = 0; rnd < 8; ++rnd) {
    int linear = rnd * 256 + tid;        // 0..2047
    int op     = linear >> 5;            // 0..63 local out row
    int d4     = (linear & 31) << 2;     // 0,4,...,124
    float4 w = *(const float4*)(W + (oBase + op) * D + d4);
    Wt[(d4 + 0) * WT_STRIDE + op] = w.x;
    Wt[(d4 + 1) * WT_STRIDE + op] = w.y;
    Wt[(d4 + 2) * WT_STRIDE + op] = w.z;
    Wt[(d4 + 3) * WT_STRIDE + op] = w.w;
  }
  {
    const float4* src = (const float4*)(Xs + s0 * D);
    float4* dst = (float4*)XsL;
    dst[tid]       = src[tid];
    dst[tid + 256] = src[tid + 256];
  }
  if (tid < SEG_PB) {
    int s   = s0 + tid;
    int rs  = graph[2 * s];
    int re  = graph[2 * s + 1];
    int nxt = (s + 1 < S) ? (graph[2 * s + 2] - 1) : (N - 1);
    re = min(re, min(nxt, N - 1));
    rs = max(rs, 0);
    cntL[tid] = (float)max(0, re - rs + 1);
  }
  __syncthreads();

  int op = tid & 63;   // local out col; whole wave shares g
  int g  = tid >> 6;   // 0..3 segment phase
  float acc[4] = {0.f, 0.f, 0.f, 0.f};

  const float4* xs4 = (const float4*)XsL;
  #pragma unroll 8
  for (int d4 = 0; d4 < D4; ++d4) {
    float w0 = Wt[(4 * d4 + 0) * WT_STRIDE + op];
    float w1 = Wt[(4 * d4 + 1) * WT_STRIDE + op];
    float w2 = Wt[(4 * d4 + 2) * WT_STRIDE + op];
    float w3 = Wt[(4 * d4 + 3) * WT_STRIDE + op];
    #pragma unroll
    for (int j = 0; j < 4; ++j) {
      float4 x = xs4[(4 * j + g) * D4 + d4];  // LDS broadcast
      acc[j] += x.x * w0 + x.y * w1 + x.z * w2 + x.w * w3;
    }
  }

  float bo = b[oBase + op];
  #pragma unroll
  for (int j = 0; j < 4; ++j) {
    int sl = 4 * j + g;
    out[(s0 + sl) * D + oBase + op] = acc[j] + cntL[sl] * bo;
  }
}

extern "C" void kernel_launch(void* const* d_in, const int* in_sizes, int n_in,
                              void* d_out, int out_size, void* d_ws, size_t ws_size,
                              hipStream_t stream) {
  const float* in    = (const float*)d_in[0];
  const int*   graph = (const int*)d_in[1];
  const float* W     = (const float*)d_in[2];
  const float* b     = (const float*)d_in[3];
  float* out = (float*)d_out;

  const int N = in_sizes[0] / D;     // 500000
  const int S = in_sizes[1] / 2;     // 10000

  float* Xs = (float*)d_ws;          // S*128 floats = 5.12 MB scratch

  int n4 = S * D4;                   // 320000 float4
  zero_xs_kernel<<<(n4 + 255) / 256, 256, 0, stream>>>((float4*)Xs, n4);

  int nWaves  = (N + WROWS - 1) / WROWS;   // 3907
  int nBlocks = (nWaves + 3) / 4;          // 977 (4 waves per block)
  seg_sum_wave_kernel<<<nBlocks, 256, 0, stream>>>(in, graph, Xs, N, S);

  dim3 grid2(S / SEG_PB, D / OUT_PB);  // 625 x 2
  seg_gemm_kernel<<<grid2, 256, 0, stream>>>(Xs, W, b, graph, out, N, S);
}